// Round 6
// baseline (83.473 us; speedup 1.0000x reference)
//
#include <hip/hip_runtime.h>

#define V 96
#define VV (V * V)
#define B_ 4
#define N_ 32
#define P_ 32
#define TPB 512                    // 8 waves
#define TILE 64                    // pixels per block
#define TILES_PER_B (VV / TILE)    // 144 -> grid = 576 blocks
#define PXL 4                      // pixels per lane (consecutive x, same row)
#define ESTRIDE (P_ * 2 + 1)       // padded float4 stride per poly (bank spread)

// Single dispatch. Wave = 4 polys x 16 lane-groups; each lane does 4 px of a
// 64-px tile for its poly. Edge reads (2 x ds_read_b128, 4 distinct addrs)
// amortized over 4 pixels -> K-loop flips from LDS-bound to VALU/LDS balanced.
__global__ __launch_bounds__(TPB) void fused_kernel(
    const float* __restrict__ poly,       // (B,N,P,2)
    const float* __restrict__ attr,       // (B,8)
    const float* __restrict__ validity,   // (B,N)
    float* __restrict__ out)              // (B,V,V,V)
{
    const int b    = blockIdx.x / TILES_PER_B;
    const int tile = blockIdx.x % TILES_PER_B;
    const int t    = threadIdx.x;
    const int wave = t >> 6;
    const int lane = t & 63;
    const int psub = lane >> 4;           // which of the wave's 4 polys
    const int xsub = lane & 15;           // which 4-px group of the tile

    // e0 = {x0, y0, ex, ey}   e1 = {exq, eyq, y1, sI}; padded stride per poly
    __shared__ float4 sE[N_ * ESTRIDE];   // 32.5 KB
    __shared__ float  red[TILE];          // tile max (uint-bit atomicMax)

    if (t < TILE) red[t] = 0.0f;

    for (int k = t; k < N_ * P_; k += TPB) {       // 2 edges per thread
        const int n = k >> 5, p = k & 31, pn = (p + 1) & 31;
        const float* base = poly + (size_t)(b * N_ + n) * (P_ * 2);
        float x0 = base[p * 2],  y0 = base[p * 2 + 1];
        float x1 = base[pn * 2], y1 = base[pn * 2 + 1];
        float ex = x1 - x0, ey = y1 - y0;
        float srq = __builtin_amdgcn_rcpf(ex * ex + ey * ey + 1e-8f);
        float sry = __builtin_amdgcn_rcpf(ey + 1e-8f);
        sE[n * ESTRIDE + p * 2]     = make_float4(x0, y0, ex, ey);
        sE[n * ESTRIDE + p * 2 + 1] = make_float4(ex * srq, ey * srq, y1, ex * sry);
    }
    __syncthreads();

    const int n  = wave * PXL + psub;              // this lane's polygon
    const float vf = (validity[b * N_ + n] >= 0.5f) ? 1.0f : 0.0f;

    if (__ballot(vf != 0.0f) != 0ull) {            // skip only if all 4 invalid
        // exact fp32 division to match numpy's grid
        const int pixb = tile * TILE + xsub * PXL; // 4|96 -> group never straddles rows
        const int row  = pixb / V;
        const int col0 = pixb - row * V;
        const float py = (float)row / 95.0f;
        float pxv[PXL];
        #pragma unroll
        for (int i = 0; i < PXL; ++i) pxv[i] = (float)(col0 + i) / 95.0f;

        float mind2[PXL] = {1e30f, 1e30f, 1e30f, 1e30f};
        int   par[PXL]   = {0, 0, 0, 0};

        #pragma unroll
        for (int p = 0; p < P_; ++p) {
            const float4 e0 = sE[n * ESTRIDE + p * 2];
            const float4 e1 = sE[n * ESTRIDE + p * 2 + 1];

            // per-edge (y-uniform across the lane's 4 px)
            float vy = py - e0.y;
            float tb = vy * e1.y;                          // vy*eyq
            float cI = fmaf(-e1.w, e0.y, e0.x);
            float ix = fmaf(e1.w, py, cI);                 // ray-edge intersection x
            bool  c0 = (e0.y <= py);
            bool  c1 = (e1.z <= py);                       // y1 exact vertex value
            int cross = (int)(c0 != c1);

            #pragma unroll
            for (int i = 0; i < PXL; ++i) {
                float vx = pxv[i] - e0.x;
                float tt = fmaf(vx, e1.x, tb);             // (v.e)/|e|^2
                tt = fminf(fmaxf(tt, 0.0f), 1.0f);
                float dx = fmaf(-tt, e0.z, vx);
                float dy = fmaf(-tt, e0.w, vy);
                mind2[i] = fminf(mind2[i], fmaf(dx, dx, dy * dy));
                par[i]  ^= (ix > pxv[i]) ? cross : 0;
            }
        }

        #pragma unroll
        for (int i = 0; i < PXL; ++i) {
            float mind = sqrtf(mind2[i]);
            float sdf  = par[i] ? -mind : mind;
            // sigmoid(-100*sdf) = rcp(1 + exp2(100*log2e*sdf))
            float m = __builtin_amdgcn_rcpf(
                1.0f + __builtin_amdgcn_exp2f(sdf * 144.26950408889634f));
            float bst = m * vf;                            // invalid poly -> 0
            // combine the wave's 4 polys (lanes xor 16 / 32)
            bst = fmaxf(bst, __shfl_xor(bst, 16));
            bst = fmaxf(bst, __shfl_xor(bst, 32));
            if (psub == 0)                                  // one lane-group commits
                atomicMax((unsigned int*)&red[xsub * PXL + i], __float_as_uint(bst));
        }
    }
    __syncthreads();

    // write phase: wave w writes depth slices d = 12w .. 12w+11 (64 contiguous
    // floats per wave-store)
    const float a  = attr[b * 8];
    const float nh = fminf(fmaxf(a, 0.0f), 1.0f);
    const float hv = fminf(fmaxf(rintf(nh * (float)V), 1.0f), (float)V); // half-even
    const float c  = red[lane];
    float* obase = out + (size_t)b * V * VV + tile * TILE + lane;
    #pragma unroll
    for (int i = 0; i < V / 8; ++i) {
        const int d = wave * (V / 8) + i;
        obase[(size_t)d * VV] = ((float)d < hv) ? c : 0.0f;
    }
}

extern "C" void kernel_launch(void* const* d_in, const int* in_sizes, int n_in,
                              void* d_out, int out_size, void* d_ws, size_t ws_size,
                              hipStream_t stream) {
    const float* polygons = (const float*)d_in[0];   // (4,32,32,2)
    const float* attrs    = (const float*)d_in[1];   // (4,8)
    const float* validity = (const float*)d_in[2];   // (4,32)
    float* out = (float*)d_out;                      // (4,96,96,96)

    fused_kernel<<<B_ * TILES_PER_B, TPB, 0, stream>>>(polygons, attrs, validity, out);
}